// Round 6
// baseline (345.479 us; speedup 1.0000x reference)
//
#include <hip/hip_runtime.h>
#include <hip/hip_bf16.h>
#include <stdint.h>

#define B_ 2
#define C_ 256
#define H_ 96
#define W_ 96
#define HW_ (H_*W_)

typedef _Float16 h2 __attribute__((ext_vector_type(2)));
typedef _Float16 h8 __attribute__((ext_vector_type(8)));
typedef unsigned int u32x4 __attribute__((ext_vector_type(4)));

union H8U { h8 v; h2 h[4]; };
union U4H { u32x4 u; h8 v; };

__device__ __forceinline__ float dot2f(h2 a, h2 b, float c) {
#if __has_builtin(__builtin_amdgcn_fdot2)
  return __builtin_amdgcn_fdot2(a, b, c, false);
#else
  return c + (float)a[0] * (float)b[0] + (float)a[1] * (float)b[1];
#endif
}

__device__ __forceinline__ h8 ntload_h8(const void* p) {
  U4H c; c.u = __builtin_nontemporal_load((const u32x4*)p); return c.v;
}

// ---------- (B, C, HW) f32  ->  (B, HW, C) f16 tile transpose (+scale) ----------
__global__ __launch_bounds__(256) void k_transpose(const float* __restrict__ in,
                                                   _Float16* __restrict__ out,
                                                   float scale) {
  __shared__ float t[32][33];
  const int b = blockIdx.z;
  const int p0 = blockIdx.x * 32, c0 = blockIdx.y * 32;
  const int tx = threadIdx.x, ty = threadIdx.y;
  const float* src = in + ((size_t)b * C_ + c0) * HW_ + p0;
#pragma unroll
  for (int i = 0; i < 4; ++i)
    t[ty + 8 * i][tx] = src[(size_t)(ty + 8 * i) * HW_ + tx];
  __syncthreads();
  _Float16* dst = out + ((size_t)b * HW_ + p0) * C_ + c0;
#pragma unroll
  for (int i = 0; i < 4; ++i)
    dst[(size_t)(ty + 8 * i) * C_ + tx] = (_Float16)(t[tx][ty + 8 * i] * scale);
}

// ---------- 2x2 avg pool on (B, h, w, C) f16 ----------
__global__ __launch_bounds__(256) void k_pool(const _Float16* __restrict__ in,
                                              _Float16* __restrict__ out,
                                              int hin, int win) {
  const int wout = win >> 1, hout = hin >> 1;
  int idx = blockIdx.x;
  const int X = idx % wout; idx /= wout;
  const int Y = idx % hout; const int b = idx / hout;
  const int c = threadIdx.x;
  const _Float16* p = in + (((size_t)b * hin + 2 * Y) * win + 2 * X) * C_ + c;
  const size_t rs = (size_t)win * C_;
  float v = (float)p[0] + (float)p[C_] + (float)p[rs] + (float)p[rs + C_];
  out[(((size_t)b * hout + Y) * wout + X) * C_ + c] = (_Float16)(v * 0.25f);
}

// workspace byte layout: [zero page 512][f1t][L0][L1][L2][L3]
#define F1OFF 512u
#define L0OFF 9437696u
#define L1OFF 18874880u
#define L2OFF 21234176u
#define L3OFF 21824000u
#define PB0 4718592u
#define PB1 1179648u
#define PB2 294912u
#define PB3 73728u

// ---------- main: per-pixel windowed dot products, L2-phased ----------
__global__ __launch_bounds__(256, 4) void k_corr(const char* __restrict__ ws,
                                                 const float* __restrict__ cent,
                                                 float* __restrict__ out) {
  __shared__ float dl[4][112];
  __shared__ uint32_t ofs[4][112];
  const int wid  = threadIdx.x >> 6;
  const int lane = threadIdx.x & 63;
  const int cg   = lane & 7;           // channel subgroup (32 ch = 4x h8)
  const int pg   = lane >> 3;          // position subgroup

  // XCD swizzle: contiguous yx range per XCD; XCDs 0-3 batch 0, 4-7 batch 1.
  const int g    = blockIdx.x;
  const int xcd  = g & 7;
  const int slot = g >> 3;             // 0..575
  const int b    = xcd >> 2;
  const int ib   = (xcd & 3) * 576 + slot;
  const int yx   = ib * 4 + wid;
  const int pix  = b * HW_ + yx;

  const float cx = __builtin_nontemporal_load(&cent[(size_t)(b * 2 + 0) * HW_ + yx]);
  const float cy = __builtin_nontemporal_load(&cent[(size_t)(b * 2 + 1) * HW_ + yx]);

  // f1 (pre-scaled by 1/16) as 16 packed h2 regs; nt loads keep L2 clean
  h2 f1h[16];
  {
    const char* fp = ws + F1OFF + (size_t)pix * 512 + cg * 16;
#pragma unroll
    for (int it = 0; it < 4; ++it) {
      H8U u; u.v = ntload_h8(fp + it * 128);
      f1h[it * 4 + 0] = u.h[0]; f1h[it * 4 + 1] = u.h[1];
      f1h[it * 4 + 2] = u.h[2]; f1h[it * 4 + 3] = u.h[3];
    }
  }

  float* ob = out + (size_t)b * 324 * HW_ + yx;

  auto do_level = [&](int hl, int wl, uint32_t lbase, float inv, float* outp) {
    const float cxl = cx * inv, cyl = cy * inv;
    const float fx = floorf(cxl), fy = floorf(cyl);
    const int X0 = (int)fx - 4, Y0 = (int)fy - 4;
    const float wx1 = cxl - fx, wy1 = cyl - fy;
    const float wx0 = 1.0f - wx1, wy0 = 1.0f - wy1;

    // per-wave offset table: 100 positions (+12 phantom -> zero page)
#pragma unroll
    for (int r = 0; r < 2; ++r) {
      const int p = r * 64 + lane;
      if (p < 112) {
        const int prow = p / 10, pcol = p - prow * 10;
        const int yy = Y0 + prow, xx = X0 + pcol;
        const bool valid = (p < 100) & (yy >= 0) & (yy < hl) & (xx >= 0) & (xx < wl);
        ofs[wid][p] = valid ? (lbase + ((uint32_t)(yy * wl + xx) << 9)) : 0u;
      }
    }
    // (same-wave LDS RAW: ordered by lgkmcnt, no barrier needed)

    for (int gq = 0; gq < 13; ++gq) {
      const uint32_t off = ofs[wid][gq * 8 + pg] + (uint32_t)cg * 16;
      const h8* hp = (const h8*)(ws + off);
      H8U u0, u1, u2, u3;
      u0.v = hp[0]; u1.v = hp[8]; u2.v = hp[16]; u3.v = hp[24];
      float a0 = 0.f, a1 = 0.f, a2 = 0.f, a3 = 0.f;
      a0 = dot2f(u0.h[0], f1h[0],  a0); a0 = dot2f(u0.h[1], f1h[1],  a0);
      a0 = dot2f(u0.h[2], f1h[2],  a0); a0 = dot2f(u0.h[3], f1h[3],  a0);
      a1 = dot2f(u1.h[0], f1h[4],  a1); a1 = dot2f(u1.h[1], f1h[5],  a1);
      a1 = dot2f(u1.h[2], f1h[6],  a1); a1 = dot2f(u1.h[3], f1h[7],  a1);
      a2 = dot2f(u2.h[0], f1h[8],  a2); a2 = dot2f(u2.h[1], f1h[9],  a2);
      a2 = dot2f(u2.h[2], f1h[10], a2); a2 = dot2f(u2.h[3], f1h[11], a2);
      a3 = dot2f(u3.h[0], f1h[12], a3); a3 = dot2f(u3.h[1], f1h[13], a3);
      a3 = dot2f(u3.h[2], f1h[14], a3); a3 = dot2f(u3.h[3], f1h[15], a3);
      float acc = (a0 + a1) + (a2 + a3);
      acc += __shfl_xor(acc, 1);
      acc += __shfl_xor(acc, 2);
      acc += __shfl_xor(acc, 4);
      const int p = gq * 8 + pg;
      if (cg == 0 && p < 100) dl[wid][p] = acc;
    }

    // separable bilinear combine + nt store
#pragma unroll
    for (int rr = 0; rr < 2; ++rr) {
      const int o = rr * 64 + lane;
      if (o < 81) {
        const int a = o / 9, bq = o - a * 9;
        const float* d = dl[wid];
        const float d00 = d[bq * 10 + a],      d10 = d[bq * 10 + a + 1];
        const float d01 = d[bq * 10 + a + 10], d11 = d[bq * 10 + a + 11];
        const float v = wy0 * (wx0 * d00 + wx1 * d10) + wy1 * (wx0 * d01 + wx1 * d11);
        __builtin_nontemporal_store(v, &outp[(size_t)o * HW_]);
      }
    }
  };

  // Phase A: levels 1-3 (working set ~1.55 MB/XCD, L2-resident)
  do_level(48, 48, L1OFF + (uint32_t)b * PB1, 0.5f,   ob + (size_t)(1 * 81) * HW_);
  do_level(24, 24, L2OFF + (uint32_t)b * PB2, 0.25f,  ob + (size_t)(2 * 81) * HW_);
  do_level(12, 12, L3OFF + (uint32_t)b * PB3, 0.125f, ob + (size_t)(3 * 81) * HW_);

  // Phase B: level 0 in two cy-half passes (rows +-halo ~2.6 MB, L2-resident)
  __syncthreads();
  if (cy < 48.0f)  do_level(96, 96, L0OFF + (uint32_t)b * PB0, 1.0f, ob);
  __syncthreads();
  if (cy >= 48.0f) do_level(96, 96, L0OFF + (uint32_t)b * PB0, 1.0f, ob);
}

extern "C" void kernel_launch(void* const* d_in, const int* in_sizes, int n_in,
                              void* d_out, int out_size, void* d_ws, size_t ws_size,
                              hipStream_t stream) {
  (void)in_sizes; (void)n_in; (void)out_size; (void)ws_size;
  const float* f1   = (const float*)d_in[0];
  const float* f2   = (const float*)d_in[1];
  const float* cent = (const float*)d_in[2];
  float* out = (float*)d_out;

  char* ws = (char*)d_ws;
  _Float16* f1t = (_Float16*)(ws + F1OFF);
  _Float16* L0  = (_Float16*)(ws + L0OFF);
  _Float16* L1  = (_Float16*)(ws + L1OFF);
  _Float16* L2  = (_Float16*)(ws + L2OFF);
  _Float16* L3  = (_Float16*)(ws + L3OFF);

  (void)hipMemsetAsync(d_ws, 0, 512, stream);  // zero page for OOB gathers

  dim3 tb(32, 8, 1);
  dim3 tg(HW_ / 32, C_ / 32, B_);
  hipLaunchKernelGGL(k_transpose, tg, tb, 0, stream, f1, f1t, 0.0625f);
  hipLaunchKernelGGL(k_transpose, tg, tb, 0, stream, f2, L0, 1.0f);
  hipLaunchKernelGGL(k_pool, dim3(B_ * 48 * 48), dim3(256), 0, stream, L0, L1, 96, 96);
  hipLaunchKernelGGL(k_pool, dim3(B_ * 24 * 24), dim3(256), 0, stream, L1, L2, 48, 48);
  hipLaunchKernelGGL(k_pool, dim3(B_ * 12 * 12), dim3(256), 0, stream, L2, L3, 24, 24);
  hipLaunchKernelGGL(k_corr, dim3(B_ * HW_ / 4), dim3(256), 0, stream, ws, cent, out);
}

// Round 7
// 150.431 us; speedup vs baseline: 2.2966x; 2.2966x over previous
//
#include <hip/hip_runtime.h>
#include <stdint.h>

#define B_ 2
#define C_ 256
#define H_ 96
#define W_ 96
#define HW_ (H_*W_)

typedef _Float16 half8 __attribute__((ext_vector_type(8)));
typedef float f32x4 __attribute__((ext_vector_type(4)));
typedef unsigned int u32x4 __attribute__((ext_vector_type(4)));

// ---- workspace byte layout ----
#define F1OFF   0u          // f16 (B,HW,C) f1, pre-scaled 1/16   9,437,184 B
#define L0OFF   9437184u    // f16 pyramid level 0 (B,h,w,C)
#define L1OFF   18874368u
#define L2OFF   21233664u
#define L3OFF   21823488u
#define SCROFF  21970944u   // f16 scr[B*HW][324]                11,943,936 B
#define CNTOFF  33914880u   // int cnt[1152]
#define OFFOFF  33919488u   // int offs[1153]
#define CUROFF  33924104u   // int cursor[1152]
#define PERMOFF 33928712u   // int perm[18432]

// ---------- (B, C, HW) f32 -> (B, HW, C) f16 transpose (+scale) ----------
__global__ __launch_bounds__(256) void k_transpose(const float* __restrict__ in,
                                                   _Float16* __restrict__ out,
                                                   float scale) {
  __shared__ float t[32][33];
  const int b = blockIdx.z;
  const int p0 = blockIdx.x * 32, c0 = blockIdx.y * 32;
  const int tx = threadIdx.x, ty = threadIdx.y;
  const float* src = in + ((size_t)b * C_ + c0) * HW_ + p0;
#pragma unroll
  for (int i = 0; i < 4; ++i)
    t[ty + 8 * i][tx] = src[(size_t)(ty + 8 * i) * HW_ + tx];
  __syncthreads();
  _Float16* dst = out + ((size_t)b * HW_ + p0) * C_ + c0;
#pragma unroll
  for (int i = 0; i < 4; ++i)
    dst[(size_t)(ty + 8 * i) * C_ + tx] = (_Float16)(t[tx][ty + 8 * i] * scale);
}

// ---------- 2x2 avg pool on (B, h, w, C) f16 ----------
__global__ __launch_bounds__(256) void k_pool(const _Float16* __restrict__ in,
                                              _Float16* __restrict__ out,
                                              int hin, int win) {
  const int wout = win >> 1, hout = hin >> 1;
  int idx = blockIdx.x;
  const int X = idx % wout; idx /= wout;
  const int Y = idx % hout; const int b = idx / hout;
  const int c = threadIdx.x;
  const _Float16* p = in + (((size_t)b * hin + 2 * Y) * win + 2 * X) * C_ + c;
  const size_t rs = (size_t)win * C_;
  float v = (float)p[0] + (float)p[C_] + (float)p[rs] + (float)p[rs + C_];
  out[(((size_t)b * hout + Y) * wout + X) * C_ + c] = (_Float16)(v * 0.25f);
}

// ---------- bucket prepass: histogram / scan / scatter ----------
__device__ __forceinline__ int cell_of(float cx, float cy, int b) {
  int ci = (int)(cx * 0.25f); ci = min(max(ci, 0), 23);
  int cj = (int)(cy * 0.25f); cj = min(max(cj, 0), 23);
  return b * 576 + cj * 24 + ci;
}

__global__ __launch_bounds__(256) void k_hist(const float* __restrict__ cent,
                                              int* __restrict__ cnt) {
  const int t = blockIdx.x * 256 + threadIdx.x;   // 0..18431
  const int b = t / HW_, yx = t - b * HW_;
  const float cx = cent[(size_t)b * 2 * HW_ + yx];
  const float cy = cent[(size_t)b * 2 * HW_ + HW_ + yx];
  atomicAdd(&cnt[cell_of(cx, cy, b)], 1);
}

__global__ __launch_bounds__(1024) void k_scan(const int* __restrict__ cnt,
                                               int* __restrict__ offs,
                                               int* __restrict__ cursor) {
  __shared__ int sh[2048];
  const int t = threadIdx.x;
  sh[t] = (t < 1152) ? cnt[t] : 0;
  sh[t + 1024] = ((t + 1024) < 1152) ? cnt[t + 1024] : 0;
  __syncthreads();
  for (int d = 1; d < 2048; d <<= 1) {
    const int v0 = (t >= d) ? sh[t - d] : 0;
    const int v1 = ((t + 1024) >= d) ? sh[t + 1024 - d] : 0;
    __syncthreads();
    sh[t] += v0; sh[t + 1024] += v1;
    __syncthreads();
  }
  if (t == 0) offs[0] = 0;
  if (t < 1152) { offs[t + 1] = sh[t]; cursor[t] = (t == 0) ? 0 : sh[t - 1]; }
  const int t2 = t + 1024;
  if (t2 < 1152) { offs[t2 + 1] = sh[t2]; cursor[t2] = sh[t2 - 1]; }
}

__global__ __launch_bounds__(256) void k_scatter(const float* __restrict__ cent,
                                                 int* __restrict__ cursor,
                                                 int* __restrict__ perm) {
  const int t = blockIdx.x * 256 + threadIdx.x;
  const int b = t / HW_, yx = t - b * HW_;
  const float cx = cent[(size_t)b * 2 * HW_ + yx];
  const float cy = cent[(size_t)b * 2 * HW_ + HW_ + yx];
  const int pos = atomicAdd(&cursor[cell_of(cx, cy, b)], 1);
  perm[pos] = t;
}

// ---------- main: per-cell slab GEMM (MFMA) + bilinear epilogue ----------
__global__ __launch_bounds__(512) void k_cell(char* __restrict__ ws,
                                              const float* __restrict__ cent) {
  __shared__ _Float16 slabA[176 * 264];  // positions x 256ch (+pad)
  __shared__ _Float16 f1s[16 * 264];     // 16 px x 256ch (+pad)
  __shared__ float dl[16 * 180];         // C tile: px x pos
  __shared__ int pixl[16];
  __shared__ float cxs[16], cys[16];

  const int cell = blockIdx.x;
  const int b = cell / 576;
  const int cib = cell - b * 576;
  const int ci = cib % 24, cj = cib / 24;

  const int* offs = (const int*)(ws + OFFOFF);
  const int* perm = (const int*)(ws + PERMOFF);
  const int beg = offs[cell], end = offs[cell + 1];
  if (beg == end) return;
  const int npix = end - beg;

  const int t = threadIdx.x;
  const int w = t >> 6, lane = t & 63;
  const int row16 = lane & 15, kb = lane >> 4;

  const uint32_t LB[4] = {L0OFF, L1OFF, L2OFF, L3OFF};
  const uint32_t PBl[4] = {4718592u, 1179648u, 294912u, 73728u};
  const int Wt[4] = {13, 11, 10, 10};

  _Float16* scr = (_Float16*)(ws + SCROFF);

  for (int lvl = 0; lvl < 4; ++lvl) {
    const int wl = 96 >> lvl;
    const int W = Wt[lvl];
    const int N = W * W;
    const int FX = (lvl < 3) ? (ci << (2 - lvl)) : (ci >> 1);
    const int FY = (lvl < 3) ? (cj << (2 - lvl)) : (cj >> 1);
    const int XU0 = FX - 4, YU0 = FY - 4;
    const char* lbase = ws + LB[lvl] + (size_t)b * PBl[lvl];

    __syncthreads();
    // stage union window slab (zero-filled OOB == reference zero padding)
    const int nseg = N * 32;
    for (int s = t; s < nseg; s += 512) {
      const int pos = s >> 5, seg = s & 31;
      const int sy = pos / W, sx = pos - sy * W;
      const int gy = YU0 + sy, gx = XU0 + sx;
      u32x4 v = {0, 0, 0, 0};
      if (gy >= 0 && gy < wl && gx >= 0 && gx < wl)
        v = *(const u32x4*)(lbase + (((size_t)gy * wl + gx) << 9) + seg * 16);
      *(u32x4*)&slabA[pos * 264 + seg * 8] = v;
    }
    __syncthreads();

    const int nmt = (npix + 15) >> 4;
    for (int mt = 0; mt < nmt; ++mt) {
      // stage 16-pixel f1 tile + meta
      {
        const int r = t >> 5, seg = t & 31;
        const int idx = beg + mt * 16 + r;
        const int pv = (idx < end) ? perm[idx] : -1;
        u32x4 v = {0, 0, 0, 0};
        if (pv >= 0) v = *(const u32x4*)(ws + F1OFF + (size_t)pv * 512 + seg * 16);
        *(u32x4*)&f1s[r * 264 + seg * 8] = v;
        if (seg == 0) {
          pixl[r] = pv;
          if (pv >= 0) {
            const int yx = pv - b * HW_;
            cxs[r] = cent[(size_t)b * 2 * HW_ + yx];
            cys[r] = cent[(size_t)b * 2 * HW_ + HW_ + yx];
          }
        }
      }
      __syncthreads();

      // GEMM: D[px][pos] = sum_k f1[px][k] * slab[pos][k]
      const int ntiles = (N + 15) >> 4;
      for (int j = w; j < ntiles; j += 8) {
        const int n0 = j * 16;
        f32x4 acc = {0.f, 0.f, 0.f, 0.f};
        const _Float16* ap = &f1s[row16 * 264 + kb * 8];
        const _Float16* bp = &slabA[(n0 + row16) * 264 + kb * 8];
#pragma unroll
        for (int k = 0; k < 8; ++k) {
          const half8 av = *(const half8*)(ap + k * 32);
          const half8 bv = *(const half8*)(bp + k * 32);
          acc = __builtin_amdgcn_mfma_f32_16x16x32_f16(av, bv, acc, 0, 0, 0);
        }
#pragma unroll
        for (int j4 = 0; j4 < 4; ++j4)
          dl[(kb * 4 + j4) * 180 + n0 + row16] = acc[j4];
      }
      __syncthreads();

      // bilinear epilogue -> scr[pix][lvl*81 + o]
      {
        const int p = t >> 5, q = t & 31;
        const int pv = pixl[p];
        if (pv >= 0) {
          const float inv = 1.0f / (float)(1 << lvl);
          const float cxl = cxs[p] * inv, cyl = cys[p] * inv;
          const float fxl = floorf(cxl), fyl = floorf(cyl);
          const float wx1 = cxl - fxl, wy1 = cyl - fyl;
          const float wx0 = 1.f - wx1, wy0 = 1.f - wy1;
          const int sxp = (int)fxl - FX, syp = (int)fyl - FY;
          const float* d = &dl[p * 180];
          _Float16* so = scr + (size_t)pv * 324 + lvl * 81;
#pragma unroll
          for (int rr = 0; rr < 3; ++rr) {
            const int o = q + rr * 32;
            if (o < 81) {
              const int a = o / 9, bq = o - a * 9;   // a = x idx, bq = y idx
              const int n = (syp + bq) * W + sxp + a;
              const float d00 = d[n], d10 = d[n + 1];
              const float d01 = d[n + W], d11 = d[n + W + 1];
              so[o] = (_Float16)(wy0 * (wx0 * d00 + wx1 * d10) +
                                 wy1 * (wx0 * d01 + wx1 * d11));
            }
          }
        }
      }
      __syncthreads();
    }
  }
}

// ---------- final transpose: scr[B*HW][324] f16 -> out[B][324][HW] f32 ----------
__global__ __launch_bounds__(256) void k_otrans(const _Float16* __restrict__ scr,
                                                float* __restrict__ out) {
  __shared__ float t[32][33];
  const int b = blockIdx.z;
  const int yx0 = blockIdx.x * 32, c0 = blockIdx.y * 32;
  const int tx = threadIdx.x, ty = threadIdx.y;
#pragma unroll
  for (int i = 0; i < 4; ++i) {
    const int yxi = ty + 8 * i, c = c0 + tx;
    t[yxi][tx] = (c < 324)
        ? (float)scr[((size_t)b * HW_ + yx0 + yxi) * 324 + c] : 0.f;
  }
  __syncthreads();
#pragma unroll
  for (int i = 0; i < 4; ++i) {
    const int c = c0 + ty + 8 * i;
    if (c < 324)
      out[((size_t)b * 324 + c) * HW_ + yx0 + tx] = t[tx][ty + 8 * i];
  }
}

extern "C" void kernel_launch(void* const* d_in, const int* in_sizes, int n_in,
                              void* d_out, int out_size, void* d_ws, size_t ws_size,
                              hipStream_t stream) {
  (void)in_sizes; (void)n_in; (void)out_size; (void)ws_size;
  const float* f1   = (const float*)d_in[0];
  const float* f2   = (const float*)d_in[1];
  const float* cent = (const float*)d_in[2];
  float* out = (float*)d_out;

  char* ws = (char*)d_ws;
  _Float16* f1t = (_Float16*)(ws + F1OFF);
  _Float16* L0  = (_Float16*)(ws + L0OFF);
  _Float16* L1  = (_Float16*)(ws + L1OFF);
  _Float16* L2  = (_Float16*)(ws + L2OFF);
  _Float16* L3  = (_Float16*)(ws + L3OFF);
  int* cnt    = (int*)(ws + CNTOFF);
  int* offs   = (int*)(ws + OFFOFF);
  int* cursor = (int*)(ws + CUROFF);
  int* perm   = (int*)(ws + PERMOFF);

  (void)hipMemsetAsync(cnt, 0, 1152 * sizeof(int), stream);

  dim3 tb(32, 8, 1);
  dim3 tg(HW_ / 32, C_ / 32, B_);
  hipLaunchKernelGGL(k_transpose, tg, tb, 0, stream, f1, f1t, 0.0625f);
  hipLaunchKernelGGL(k_transpose, tg, tb, 0, stream, f2, L0, 1.0f);
  hipLaunchKernelGGL(k_pool, dim3(B_ * 48 * 48), dim3(256), 0, stream, L0, L1, 96, 96);
  hipLaunchKernelGGL(k_pool, dim3(B_ * 24 * 24), dim3(256), 0, stream, L1, L2, 48, 48);
  hipLaunchKernelGGL(k_pool, dim3(B_ * 12 * 12), dim3(256), 0, stream, L2, L3, 24, 24);

  hipLaunchKernelGGL(k_hist, dim3(72), dim3(256), 0, stream, cent, cnt);
  hipLaunchKernelGGL(k_scan, dim3(1), dim3(1024), 0, stream, cnt, offs, cursor);
  hipLaunchKernelGGL(k_scatter, dim3(72), dim3(256), 0, stream, cent, cursor, perm);

  hipLaunchKernelGGL(k_cell, dim3(1152), dim3(512), 0, stream, ws, cent);

  hipLaunchKernelGGL(k_otrans, dim3(HW_ / 32, 11, B_), tb, 0, stream,
                     (const _Float16*)(ws + SCROFF), out);
}